// Round 8
// baseline (247.770 us; speedup 1.0000x reference)
//
#include <hip/hip_runtime.h>

// norm_conv: im2col(3x3 reflect) -> row-normalize -> GEMM[576x64], fused.
// Design: out = (patches@W - mean*colsum(W)) * inv_std.
//  - kernel 1: pre-pack W (fp32->bf16) into per-lane MFMA fragment layout in ws.
//  - kernel 2: 512 blocks (HALF image each => 2 blocks/CU), 256 thr (4 waves),
//    PRODUCER/CONSUMER WAVE SPECIALIZATION:
//      waves 0,1 (consumers): hold W frags (144 regs) for one 32-channel half
//        each, run stats + MFMA + epilogue stores.
//      waves 2,3 (producers): no W frags; stream global->f2bf->LDS + per-pixel
//        channel sums, staging section s+1 WHILE consumers compute section s.
//  - Round-7: KS-OUTER over groups of 2 m-tiles: per ks, 4 ds_read_b64 +
//    4 MFMAs into 4 INDEPENDENT acc chains (round 5 had 2 chains, fully
//    serialized ds_read->MFMA; round 6 tried 8 chains and SPILLED at
//    acc[4][2]+af[4]: VGPR 128+AGPR 176 > 256 cap -> 152us scratch storm).
//    Register budget: bfrag 144 + acc[2][2] 16 = 160 persistent + af[2] 8
//    transient -> arch VGPR ~110, headroom for cross-ks read hoisting.
//    __launch_bounds__(256,2): proven no-spill budget. VGPR_Count alarm: 128.
//  - ALL __syncthreads() AT UNIFORM TOP-LEVEL POINTS (round-3 lesson).
//  - LDS row RING (10 slots, slot(r)=(r+1)%10 for block-local row r=-1..16,
//    holding input row reflect32(half*16+r)): producers append exactly 4 rows
//    per section; consumer section s reads local rows 4s-1..4s+4, producer
//    writes 4s+5..4s+8 -> disjoint slot sets. ONE barrier per section.
//  - MFMA operands swapped: mfma(Wfrag, patchfrag) -> D^T[row=channel][col=pixel];
//    stores are pixel-contiguous full 64B lines; mean/inv lane-uniform per tile.

#define STRIDE 68            // ushorts per pixel in LDS (136 B -> 2-way banked only)
#define SLOTS  10            // ring row-slots (6 live + 4 being written)

typedef __attribute__((ext_vector_type(8))) short bf16x8;
typedef __attribute__((ext_vector_type(4))) short bf16x4;
typedef __attribute__((ext_vector_type(4))) float f32x4;

__device__ __forceinline__ unsigned short f2bf(float f) {
    union { float f; unsigned u; } v; v.f = f;
    unsigned r = v.u + 0x7FFFu + ((v.u >> 16) & 1u);   // RNE
    return (unsigned short)(r >> 16);
}
__device__ __forceinline__ unsigned pack2(float a, float b) {
    return (unsigned)f2bf(a) | ((unsigned)f2bf(b) << 16);
}
__device__ __forceinline__ int reflect32(int x) {      // jnp.pad 'reflect', pad=1
    x = (x < 0) ? -x : x;
    return (x > 31) ? (62 - x) : x;
}

// ws layout: uint4 wf[4][18][64]  (ntg, ks, lane) -> 8 bf16 frag elements.
// W[k'][o]: o = ntg*16 + (lane&15), k' = ks*32 + (lane>>4)*8 + j,
// with reordered k' = (kh*3+kw)*64 + c  <->  reference k = c*9 + (kh*3+kw).
__global__ void reorder_w_kernel(const float* __restrict__ W, uint4* __restrict__ wf) {
    int idx = blockIdx.x * 256 + threadIdx.x;   // 0..4607
    if (idx >= 4608) return;
    int lane = idx & 63;
    int ks   = (idx >> 6) % 18;
    int ntg  = idx / 1152;
    int quad = lane >> 4;
    int o    = ntg * 16 + (lane & 15);
    unsigned short v[8];
    #pragma unroll
    for (int j = 0; j < 8; ++j) {
        int kp = ks * 32 + quad * 8 + j;
        int c  = kp & 63;
        int s  = kp >> 6;
        v[j] = f2bf(W[(c * 9 + s) * 64 + o]);
    }
    uint4 r;
    r.x = (unsigned)v[0] | ((unsigned)v[1] << 16);
    r.y = (unsigned)v[2] | ((unsigned)v[3] << 16);
    r.z = (unsigned)v[4] | ((unsigned)v[5] << 16);
    r.w = (unsigned)v[6] | ((unsigned)v[7] << 16);
    wf[idx] = r;
}

__global__ __launch_bounds__(256, 2)
void norm_conv_kernel(const float* __restrict__ a,
                      const uint4* __restrict__ wf,
                      float* __restrict__ out) {
    __shared__ unsigned short img[SLOTS * 32 * STRIDE];   // 43,520 B ring
    __shared__ float csum[SLOTS * 32];                    // 1,280 B ring
    __shared__ float cssq[SLOTS * 32];                    // 1,280 B ring
    __shared__ float pairs[2][256];                       // per-consumer-wave (mean,inv)x128

    const int tid   = threadIdx.x;
    const int b     = blockIdx.x >> 1;
    const int half  = blockIdx.x & 1;       // half-image: out rows half*16..half*16+15
    const int rbase = half * 16;
    const int lane  = tid & 63;
    const int wid   = tid >> 6;             // 4 waves
    const int quad  = lane >> 4;
    const int mlan  = lane & 15;
    const float* Ab = a + (size_t)b * 65536;

    const bool is_prod = (wid >= 2);
    const int  ng = wid;                    // consumer: 32-channel half (0 or 1)
    const int  pl = (wid - 2) * 64 + lane;  // producer: 0..127

    // consumer-only state (producers never touch it)
    bf16x8 bfrag[2][18];
    float so0[4], so1[4];
    int colb[2][3];                         // lane-dep col byte offsets (const-indexed)

    if (is_prod) {
        // ---- prologue: local rows -1..4 into slots 0..5 (192 px) ----
        for (int i = pl; i < 192; i += 128) {
            int vr  = i >> 5;                    // slot = vr; holds row reflect(rbase+vr-1)
            int col = i & 31;
            const float* src = Ab + reflect32(rbase + vr - 1) * 32 + col;
            unsigned short* dst = &img[(vr * 32 + col) * STRIDE];
            float s = 0.f, q = 0.f;
            #pragma unroll 8
            for (int c = 0; c < 64; c += 2) {
                float v0 = src[c * 1024];        // coalesced: lanes -> consecutive cols
                float v1 = src[(c + 1) * 1024];
                s += v0 + v1;
                q += v0 * v0 + v1 * v1;
                *(unsigned*)&dst[c] = pack2(v0, v1);
            }
            csum[vr * 32 + col] = s;
            cssq[vr * 32 + col] = q;
        }
    } else {
        // ---- W fragments for this ng: 2 n-tiles x 18 k-steps (144 regs) ----
        #pragma unroll
        for (int nt = 0; nt < 2; ++nt) {
            #pragma unroll
            for (int ks = 0; ks < 18; ++ks) {
                union { uint4 u; bf16x8 v; } cvt;
                cvt.u = wf[((ng * 2 + nt) * 18 + ks) * 64 + lane];
                bfrag[nt][ks] = cvt.v;
            }
        }
        // colsum(W_bf16): exact vs the bf16 GEMM; distribute via shfl (no LDS)
        float So[2];
        #pragma unroll
        for (int nt = 0; nt < 2; ++nt) {
            float s = 0.f;
            #pragma unroll
            for (int ks = 0; ks < 18; ++ks) {
                #pragma unroll
                for (int j = 0; j < 8; ++j) {
                    union { unsigned u; float f; } cv;
                    cv.u = ((unsigned)(unsigned short)bfrag[nt][ks][j]) << 16;
                    s += cv.f;
                }
            }
            s += __shfl_xor(s, 16, 64);          // sum quad k'-subsets
            s += __shfl_xor(s, 32, 64);
            So[nt] = s;                          // colsum for o = ng*32+nt*16+mlan
        }
        #pragma unroll
        for (int r = 0; r < 4; ++r) {
            so0[r] = __shfl(So[0], quad * 4 + r, 64);
            so1[r] = __shfl(So[1], quad * 4 + r, 64);
        }
        // lane col byte offsets: col(h,kw) = reflect32(h*16 + mlan + kw - 1)
        #pragma unroll
        for (int h = 0; h < 2; ++h)
            #pragma unroll
            for (int kw = 0; kw < 3; ++kw)
                colb[h][kw] = (reflect32(h * 16 + mlan + kw - 1) * STRIDE + quad * 8) * 2;
    }

    __syncthreads();                        // UNIFORM: prologue staging complete

    const char* imgc = (const char*)img;
    for (int s8 = 0; s8 < 4; ++s8) {
        if (is_prod) {
            // ---- stage 4 rows (local rows 4s+5..4s+8) for section s8+1 ----
            if (s8 < 3) {
                int pb  = (4 * s8 + 6) % 10;     // slot of local row 4*s8+5
                int dr  = pl >> 5;               // 0..3
                int col = pl & 31;
                int sl  = pb + dr; if (sl >= 10) sl -= 10;
                const float* src = Ab + reflect32(rbase + 4 * s8 + 5 + dr) * 32 + col;
                unsigned short* dst = &img[(sl * 32 + col) * STRIDE];
                float s = 0.f, q = 0.f;
                #pragma unroll 8
                for (int c = 0; c < 64; c += 2) {
                    float v0 = src[c * 1024];
                    float v1 = src[(c + 1) * 1024];
                    s += v0 + v1;
                    q += v0 * v0 + v1 * v1;
                    *(unsigned*)&dst[c] = pack2(v0, v1);
                }
                csum[sl * 32 + col] = s;
                cssq[sl * 32 + col] = q;
            }
        } else {
            const int bm = (4 * s8) % 10;        // slot of local row 4*s8-1
            // ---- stats for this section's 128 px (own-wave copy, no sync) ----
            #pragma unroll
            for (int t = 0; t < 2; ++t) {
                int lp = lane + t * 64;
                int rl = lp >> 5, cg = lp & 31;
                float s = 0.f, q = 0.f;
                #pragma unroll
                for (int kh = 0; kh < 3; ++kh) {
                    int sl = bm + rl + kh; if (sl >= 10) sl -= 10;
                    int rb = sl * 32;
                    #pragma unroll
                    for (int kw = 0; kw < 3; ++kw) {
                        int p = rb + reflect32(cg + kw - 1);
                        s += csum[p];
                        q += cssq[p];
                    }
                }
                float mean = s * (1.0f / 576.0f);
                float var  = (q - s * mean) * (1.0f / 575.0f);   // ddof=1
                pairs[ng][lp * 2]     = mean;
                pairs[ng][lp * 2 + 1] = rsqrtf(var);
            }
            // ---- wave-uniform row byte offsets for local rows 4s8-1 .. 4s8+4 ----
            int rowb[6];
            #pragma unroll
            for (int j = 0; j < 6; ++j) {
                int sl = bm + j; if (sl >= 10) sl -= 10;
                rowb[j] = sl * 32 * STRIDE * 2;
            }
            // ---- 4 groups x 2 m-tiles, KS-OUTER: 4 indep acc chains/group ----
            float* outB = out + (size_t)b * 65536 + half * 512 + s8 * 128;
            #pragma unroll
            for (int g = 0; g < 4; ++g) {
                f32x4 acc[2][2];
                #pragma unroll
                for (int u = 0; u < 2; ++u) {
                    acc[u][0] = (f32x4){0.f, 0.f, 0.f, 0.f};
                    acc[u][1] = (f32x4){0.f, 0.f, 0.f, 0.f};
                }
                #pragma unroll
                for (int ks = 0; ks < 18; ++ks) {
                    const int s  = ks >> 1;           // spatial offset 0..8
                    const int kh = s / 3, kw = s % 3; // compile-time after unroll
                    const int hk = (ks & 1) * 64;     // +32 channels on odd ks
                    bf16x8 af[2];
                    #pragma unroll
                    for (int u = 0; u < 2; ++u) {
                        const int tt = g * 2 + u;
                        const int rl = tt >> 1, h = tt & 1;
                        int off = rowb[rl + kh] + colb[h][kw] + hk;
                        bf16x4 flo = *(const bf16x4*)(imgc + off);      // ds_read_b64
                        bf16x4 fhi = *(const bf16x4*)(imgc + off + 8);  // ds_read_b64
                        af[u] = __builtin_shufflevector(flo, fhi, 0, 1, 2, 3, 4, 5, 6, 7);
                    }
                    #pragma unroll
                    for (int u = 0; u < 2; ++u) {
                        acc[u][0] = __builtin_amdgcn_mfma_f32_16x16x32_bf16(bfrag[0][ks], af[u], acc[u][0], 0, 0, 0);
                        acc[u][1] = __builtin_amdgcn_mfma_f32_16x16x32_bf16(bfrag[1][ks], af[u], acc[u][1], 0, 0, 0);
                    }
                }
                // epilogue: D^T -> 16 lanes store 16 consecutive px of one channel
                #pragma unroll
                for (int u = 0; u < 2; ++u) {
                    const int tt = g * 2 + u;
                    const int lp = tt * 16 + mlan;
                    float2 mi = *(const float2*)&pairs[ng][lp * 2];  // (mean, inv)
                    float* op = outB + lp;
                    #pragma unroll
                    for (int r = 0; r < 4; ++r) {
                        int oA = ng * 32 + quad * 4 + r;
                        op[oA * 1024]        = (acc[u][0][r] - mi.x * so0[r]) * mi.y;
                        op[(oA + 16) * 1024] = (acc[u][1][r] - mi.x * so1[r]) * mi.y;
                    }
                }
            }
        }
        if (s8 < 3) __syncthreads();        // UNIFORM: section handoff
    }
}

extern "C" void kernel_launch(void* const* d_in, const int* in_sizes, int n_in,
                              void* d_out, int out_size, void* d_ws, size_t ws_size,
                              hipStream_t stream) {
    const float* a = (const float*)d_in[0];
    const float* w = (const float*)d_in[1];
    float* out = (float*)d_out;
    uint4* wf = (uint4*)d_ws;                      // needs 4608*16 = 73,728 B
    reorder_w_kernel<<<dim3(18), dim3(256), 0, stream>>>(w, wf);
    norm_conv_kernel<<<dim3(512), dim3(256), 0, stream>>>(a, (const uint4*)wf, out);
}

// Round 9
// 175.173 us; speedup vs baseline: 1.4144x; 1.4144x over previous
//
#include <hip/hip_runtime.h>

// norm_conv: im2col(3x3 reflect) -> row-normalize -> GEMM[576x64], fused.
// Design: out = (patches@W - mean*colsum(W)) * inv_std.
//  - kernel 1: pre-pack W (fp32->bf16) into per-lane MFMA fragment layout in ws.
//  - kernel 2: 512 blocks (HALF image each => 2 blocks/CU), 512 thr (8 waves):
//      waves 0-3 (consumers): ONE n-tile each (o in [wid*16, wid*16+16)),
//        bfrag[18] = 72 regs (HALF of rounds 5-7's 144 -> the register wall
//        that killed every ILP attempt is gone). Stats + MFMA + stores.
//      waves 4-7 (producers): stream global->f2bf->LDS ring + channel sums,
//        2 lanes per pixel (32 ch each, shfl-combined).
//    Per SIMD: 2 consumer waves x 2 chains + 2 producer waves -> 4 indep
//    MFMA chains + wave-level latency round-robin (rounds 4/5/7 had 1
//    consumer wave/SIMD; rounds 6/7 tried in-wave chains and spilled at
//    the 112+144=256 budget). __launch_bounds__(512,2): 128 regs/wave cap,
//    consumer ~115. VGPR alarm threshold: ~100+.
//  - ALL __syncthreads() AT UNIFORM TOP-LEVEL POINTS (round-3 lesson).
//  - LDS row RING (10 slots, slot(r)=(r+1)%10 for block-local row r=-1..16,
//    holding input row reflect32(half*16+r)): producers append exactly 4 rows
//    per section; consumer section s reads local rows 4s-1..4s+4, producer
//    writes 4s+5..4s+8 -> disjoint slot sets. ONE barrier per section.
//  - MFMA operands swapped: mfma(Wfrag, patchfrag) -> D^T[row=channel][col=pixel];
//    stores are pixel-contiguous full 64B lines; mean/inv lane-uniform per tile.

#define STRIDE 68            // ushorts per pixel in LDS (136 B -> 2-way banked only)
#define SLOTS  10            // ring row-slots (6 live + 4 being written)

typedef __attribute__((ext_vector_type(8))) short bf16x8;
typedef __attribute__((ext_vector_type(4))) short bf16x4;
typedef __attribute__((ext_vector_type(4))) float f32x4;

__device__ __forceinline__ unsigned short f2bf(float f) {
    union { float f; unsigned u; } v; v.f = f;
    unsigned r = v.u + 0x7FFFu + ((v.u >> 16) & 1u);   // RNE
    return (unsigned short)(r >> 16);
}
__device__ __forceinline__ unsigned pack2(float a, float b) {
    return (unsigned)f2bf(a) | ((unsigned)f2bf(b) << 16);
}
__device__ __forceinline__ int reflect32(int x) {      // jnp.pad 'reflect', pad=1
    x = (x < 0) ? -x : x;
    return (x > 31) ? (62 - x) : x;
}

// ws layout: uint4 wf[4][18][64]  (ntg, ks, lane) -> 8 bf16 frag elements.
// W[k'][o]: o = ntg*16 + (lane&15), k' = ks*32 + (lane>>4)*8 + j,
// with reordered k' = (kh*3+kw)*64 + c  <->  reference k = c*9 + (kh*3+kw).
__global__ void reorder_w_kernel(const float* __restrict__ W, uint4* __restrict__ wf) {
    int idx = blockIdx.x * 256 + threadIdx.x;   // 0..4607
    if (idx >= 4608) return;
    int lane = idx & 63;
    int ks   = (idx >> 6) % 18;
    int ntg  = idx / 1152;
    int quad = lane >> 4;
    int o    = ntg * 16 + (lane & 15);
    unsigned short v[8];
    #pragma unroll
    for (int j = 0; j < 8; ++j) {
        int kp = ks * 32 + quad * 8 + j;
        int c  = kp & 63;
        int s  = kp >> 6;
        v[j] = f2bf(W[(c * 9 + s) * 64 + o]);
    }
    uint4 r;
    r.x = (unsigned)v[0] | ((unsigned)v[1] << 16);
    r.y = (unsigned)v[2] | ((unsigned)v[3] << 16);
    r.z = (unsigned)v[4] | ((unsigned)v[5] << 16);
    r.w = (unsigned)v[6] | ((unsigned)v[7] << 16);
    wf[idx] = r;
}

__global__ __launch_bounds__(512, 2)
void norm_conv_kernel(const float* __restrict__ a,
                      const uint4* __restrict__ wf,
                      float* __restrict__ out) {
    __shared__ unsigned short img[SLOTS * 32 * STRIDE];   // 43,520 B ring
    __shared__ float csum[SLOTS * 32];                    // 1,280 B ring
    __shared__ float cssq[SLOTS * 32];                    // 1,280 B ring
    __shared__ float pairs[4][256];                       // per-consumer-wave (mean,inv)x128

    const int tid   = threadIdx.x;
    const int b     = blockIdx.x >> 1;
    const int half  = blockIdx.x & 1;       // half-image: out rows half*16..half*16+15
    const int rbase = half * 16;
    const int lane  = tid & 63;
    const int wid   = tid >> 6;             // 8 waves
    const int quad  = lane >> 4;
    const int mlan  = lane & 15;
    const float* Ab = a + (size_t)b * 65536;

    const bool is_prod = (wid >= 4);
    const int  pl = tid & 255;              // producer lane id 0..255

    // consumer-only state (producers never touch it)
    bf16x8 bfrag[18];                       // 72 regs: ONE n-tile (o = wid*16 + mlan)
    float so[4];
    int colb[2][3];                         // lane-dep col byte offsets (const-indexed)

    if (is_prod) {
        // ---- prologue: local rows -1..4 into slots 0..5 (192 px x 2 halves) ----
        for (int i = pl; i < 384; i += 256) {
            int h   = i & 1;                     // channel half
            int px  = i >> 1;                    // 0..191
            int vr  = px >> 5;                   // slot = vr; holds row reflect(rbase+vr-1)
            int col = px & 31;
            const float* src = Ab + reflect32(rbase + vr - 1) * 32 + col + h * 32768;
            unsigned short* dst = &img[(vr * 32 + col) * STRIDE + h * 32];
            float s = 0.f, q = 0.f;
            #pragma unroll 8
            for (int c = 0; c < 32; c += 2) {
                float v0 = src[c * 1024];        // coalesced within same-h lanes
                float v1 = src[(c + 1) * 1024];
                s += v0 + v1;
                q += v0 * v0 + v1 * v1;
                *(unsigned*)&dst[c] = pack2(v0, v1);
            }
            s += __shfl_xor(s, 1, 64);           // combine the two channel halves
            q += __shfl_xor(q, 1, 64);
            if (h == 0) { csum[vr * 32 + col] = s; cssq[vr * 32 + col] = q; }
        }
    } else {
        // ---- W fragments for n-tile wid: 18 k-steps (72 regs) ----
        #pragma unroll
        for (int ks = 0; ks < 18; ++ks) {
            union { uint4 u; bf16x8 v; } cvt;
            cvt.u = wf[(wid * 18 + ks) * 64 + lane];
            bfrag[ks] = cvt.v;
        }
        // colsum(W_bf16) for o = wid*16 + mlan (exact vs the bf16 GEMM)
        float So = 0.f;
        #pragma unroll
        for (int ks = 0; ks < 18; ++ks) {
            #pragma unroll
            for (int j = 0; j < 8; ++j) {
                union { unsigned u; float f; } cv;
                cv.u = ((unsigned)(unsigned short)bfrag[ks][j]) << 16;
                So += cv.f;
            }
        }
        So += __shfl_xor(So, 16, 64);            // sum quad k'-subsets
        So += __shfl_xor(So, 32, 64);
        #pragma unroll
        for (int r = 0; r < 4; ++r)
            so[r] = __shfl(So, quad * 4 + r, 64);   // colsum for o = wid*16+quad*4+r
        // lane col byte offsets: col(h,kw) = reflect32(h*16 + mlan + kw - 1)
        #pragma unroll
        for (int h = 0; h < 2; ++h)
            #pragma unroll
            for (int kw = 0; kw < 3; ++kw)
                colb[h][kw] = (reflect32(h * 16 + mlan + kw - 1) * STRIDE + quad * 8) * 2;
    }

    __syncthreads();                        // UNIFORM: prologue staging complete

    const char* imgc = (const char*)img;
    for (int s8 = 0; s8 < 4; ++s8) {
        if (is_prod) {
            // ---- stage 4 rows (local rows 4s+5..4s+8) for section s8+1 ----
            if (s8 < 3) {
                int h   = pl & 1;
                int px  = pl >> 1;               // 0..127
                int dr  = px >> 5;               // 0..3
                int col = px & 31;
                int pb  = (4 * s8 + 6) % 10;     // slot of local row 4*s8+5
                int sl  = pb + dr; if (sl >= 10) sl -= 10;
                const float* src = Ab + reflect32(rbase + 4 * s8 + 5 + dr) * 32 + col + h * 32768;
                unsigned short* dst = &img[(sl * 32 + col) * STRIDE + h * 32];
                float s = 0.f, q = 0.f;
                #pragma unroll 8
                for (int c = 0; c < 32; c += 2) {
                    float v0 = src[c * 1024];
                    float v1 = src[(c + 1) * 1024];
                    s += v0 + v1;
                    q += v0 * v0 + v1 * v1;
                    *(unsigned*)&dst[c] = pack2(v0, v1);
                }
                s += __shfl_xor(s, 1, 64);
                q += __shfl_xor(q, 1, 64);
                if (h == 0) { csum[sl * 32 + col] = s; cssq[sl * 32 + col] = q; }
            }
        } else {
            const int bm = (4 * s8) % 10;        // slot of local row 4*s8-1
            // ---- stats for this section's 128 px (own-wave copy, no sync) ----
            #pragma unroll
            for (int t = 0; t < 2; ++t) {
                int lp = lane + t * 64;
                int rl = lp >> 5, cg = lp & 31;
                float s = 0.f, q = 0.f;
                #pragma unroll
                for (int kh = 0; kh < 3; ++kh) {
                    int sl = bm + rl + kh; if (sl >= 10) sl -= 10;
                    int rb = sl * 32;
                    #pragma unroll
                    for (int kw = 0; kw < 3; ++kw) {
                        int p = rb + reflect32(cg + kw - 1);
                        s += csum[p];
                        q += cssq[p];
                    }
                }
                float mean = s * (1.0f / 576.0f);
                float var  = (q - s * mean) * (1.0f / 575.0f);   // ddof=1
                pairs[wid][lp * 2]     = mean;
                pairs[wid][lp * 2 + 1] = rsqrtf(var);
            }
            // ---- wave-uniform row byte offsets for local rows 4s8-1 .. 4s8+4 ----
            int rowb[6];
            #pragma unroll
            for (int j = 0; j < 6; ++j) {
                int sl = bm + j; if (sl >= 10) sl -= 10;
                rowb[j] = sl * 32 * STRIDE * 2;
            }
            // ---- 4 groups x 2 m-tiles (same row), KS-OUTER: 2 indep chains ----
            float* outB = out + (size_t)b * 65536 + half * 512 + s8 * 128;
            #pragma unroll
            for (int g = 0; g < 4; ++g) {
                f32x4 acc0 = {0.f, 0.f, 0.f, 0.f};
                f32x4 acc1 = {0.f, 0.f, 0.f, 0.f};
                #pragma unroll
                for (int ks = 0; ks < 18; ++ks) {
                    const int s  = ks >> 1;           // spatial offset 0..8
                    const int kh = s / 3, kw = s % 3; // compile-time after unroll
                    const int hk = (ks & 1) * 64;     // +32 channels on odd ks
                    const int rb = rowb[g + kh];
                    int off0 = rb + colb[0][kw] + hk;
                    int off1 = rb + colb[1][kw] + hk;
                    bf16x4 flo0 = *(const bf16x4*)(imgc + off0);
                    bf16x4 fhi0 = *(const bf16x4*)(imgc + off0 + 8);
                    bf16x4 flo1 = *(const bf16x4*)(imgc + off1);
                    bf16x4 fhi1 = *(const bf16x4*)(imgc + off1 + 8);
                    bf16x8 af0 = __builtin_shufflevector(flo0, fhi0, 0, 1, 2, 3, 4, 5, 6, 7);
                    bf16x8 af1 = __builtin_shufflevector(flo1, fhi1, 0, 1, 2, 3, 4, 5, 6, 7);
                    acc0 = __builtin_amdgcn_mfma_f32_16x16x32_bf16(bfrag[ks], af0, acc0, 0, 0, 0);
                    acc1 = __builtin_amdgcn_mfma_f32_16x16x32_bf16(bfrag[ks], af1, acc1, 0, 0, 0);
                }
                // epilogue: D^T -> 16 lanes store 16 consecutive px of one channel
                #pragma unroll
                for (int u = 0; u < 2; ++u) {
                    const int tt = g * 2 + u;
                    const int lp = tt * 16 + mlan;
                    float2 mi = *(const float2*)&pairs[wid][lp * 2];  // (mean, inv)
                    float* op = outB + lp;
                    const f32x4& A = u ? acc1 : acc0;
                    #pragma unroll
                    for (int r = 0; r < 4; ++r) {
                        int oA = wid * 16 + quad * 4 + r;
                        op[oA * 1024] = (A[r] - mi.x * so[r]) * mi.y;
                    }
                }
            }
        }
        if (s8 < 3) __syncthreads();        // UNIFORM: section handoff
    }
}

extern "C" void kernel_launch(void* const* d_in, const int* in_sizes, int n_in,
                              void* d_out, int out_size, void* d_ws, size_t ws_size,
                              hipStream_t stream) {
    const float* a = (const float*)d_in[0];
    const float* w = (const float*)d_in[1];
    float* out = (float*)d_out;
    uint4* wf = (uint4*)d_ws;                      // needs 4608*16 = 73,728 B
    reorder_w_kernel<<<dim3(18), dim3(256), 0, stream>>>(w, wf);
    norm_conv_kernel<<<dim3(512), dim3(512), 0, stream>>>(a, (const uint4*)wf, out);
}